// Round 1
// baseline (1283.215 us; speedup 1.0000x reference)
//
#include <hip/hip_runtime.h>
#include <float.h>
#include <math.h>

#define NQ    64      // batch / query count
#define DF    256     // feature dim
#define CC    345     // class dim
#define CPADD 352     // class dim padded to multiple of 32
#define KT    32      // k-tile
#define EPSN  1e-12f

// ---------------- block-wide reductions (any blockDim multiple of 64) -----
__device__ __forceinline__ float blockReduceSum(float v, float* sbuf) {
  __syncthreads();
  #pragma unroll
  for (int o = 32; o > 0; o >>= 1) v += __shfl_down(v, o);
  int w = threadIdx.x >> 6;
  if ((threadIdx.x & 63) == 0) sbuf[w] = v;
  __syncthreads();
  if (threadIdx.x == 0) {
    float s = 0.f;
    int nw = blockDim.x >> 6;
    for (int i = 0; i < nw; ++i) s += sbuf[i];
    sbuf[0] = s;
  }
  __syncthreads();
  return sbuf[0];
}

__device__ __forceinline__ float blockReduceMax(float v, float* sbuf) {
  __syncthreads();
  #pragma unroll
  for (int o = 32; o > 0; o >>= 1) v = fmaxf(v, __shfl_down(v, o));
  int w = threadIdx.x >> 6;
  if ((threadIdx.x & 63) == 0) sbuf[w] = v;
  __syncthreads();
  if (threadIdx.x == 0) {
    float s = -FLT_MAX;
    int nw = blockDim.x >> 6;
    for (int i = 0; i < nw; ++i) s = fmaxf(s, sbuf[i]);
    sbuf[0] = s;
  }
  __syncthreads();
  return sbuf[0];
}

// ---------------- top-k insert, list sorted (value desc, index asc) -------
template<int T>
__device__ __forceinline__ void topk_insert(float v, int id, float (&lv)[T], int (&li)[T]) {
  // better(a) == a should sit above b
  if (!((v > lv[T-1]) || (v == lv[T-1] && id < li[T-1]))) return;
  #pragma unroll
  for (int p = T-1; p > 0; --p) {
    bool up = (v > lv[p-1]) || (v == lv[p-1] && id < li[p-1]);
    if (up) { lv[p] = lv[p-1]; li[p] = li[p-1]; }
    else    { lv[p] = v; li[p] = id; return; }
  }
  lv[0] = v; li[0] = id;
}

// ---------------- rowmap fill ---------------------------------------------
__global__ void fill_rowmap(int* rowmap, int n) {
  int i = blockIdx.x * blockDim.x + threadIdx.x;
  if (i < n) rowmap[i] = -1;
}

// ---------------- prep: softmax, normalize queries, momentum rows ---------
__global__ __launch_bounds__(384) void prep_kernel(
    const float* __restrict__ tf,     // [64][256]
    const float* __restrict__ fc1,    // [64][345]
    const float* __restrict__ fc2,    // [64][345]
    const int*   __restrict__ idx,    // [64]
    const float* __restrict__ featm,  // [N][256]
    const float* __restrict__ fc1m,   // [N][345]
    const float* __restrict__ fc2m,   // [N][345]
    float* __restrict__ Qt_feat,      // [256][64]  normalized feature queries, k-major
    float* __restrict__ Qt_fc1,       // [352][64]
    float* __restrict__ Qt_fc2,       // [352][64]
    float* __restrict__ featU,        // [64][256]  momentum-updated rows (raw)
    float* __restrict__ fc1U,         // [64][345]
    float* __restrict__ fc2U,         // [64][345]
    int*   __restrict__ rowmap)       // [N]
{
  __shared__ float sbuf[8];
  int b = blockIdx.x;      // query row
  int t = threadIdx.x;     // 0..383
  int trow = idx[b];

  // ---- feature query ----
  float x = (t < DF) ? tf[b * DF + t] : 0.f;
  float ss = blockReduceSum(x * x, sbuf);
  float inv = 1.f / fmaxf(sqrtf(ss), EPSN);
  if (t < DF) {
    Qt_feat[t * NQ + b] = x * inv;
    featU[b * DF + t] = 0.9f * featm[(size_t)trow * DF + t] + 0.1f * x;
  }

  // ---- fc1: softmax -> update row + normalized query ----
  {
    float y = (t < CC) ? fc1[b * CC + t] : -FLT_MAX;
    float mx = blockReduceMax(y, sbuf);
    float e = (t < CC) ? expf(y - mx) : 0.f;
    float se = blockReduceSum(e, sbuf);
    float s = e / se;
    float s2 = blockReduceSum(s * s, sbuf);
    float inv2 = 1.f / fmaxf(sqrtf(s2), EPSN);
    if (t < CPADD) Qt_fc1[t * NQ + b] = (t < CC) ? s * inv2 : 0.f;
    if (t < CC) fc1U[b * CC + t] = 0.9f * fc1m[(size_t)trow * CC + t] + 0.1f * s;
  }
  // ---- fc2 ----
  {
    float y = (t < CC) ? fc2[b * CC + t] : -FLT_MAX;
    float mx = blockReduceMax(y, sbuf);
    float e = (t < CC) ? expf(y - mx) : 0.f;
    float se = blockReduceSum(e, sbuf);
    float s = e / se;
    float s2 = blockReduceSum(s * s, sbuf);
    float inv2 = 1.f / fmaxf(sqrtf(s2), EPSN);
    if (t < CPADD) Qt_fc2[t * NQ + b] = (t < CC) ? s * inv2 : 0.f;
    if (t < CC) fc2U[b * CC + t] = 0.9f * fc2m[(size_t)trow * CC + t] + 0.1f * s;
  }

  if (t == 0) rowmap[trow] = b;
}

// ---------------- cos-sim GEMM (64 q x 64 rows per block) + block top-T ---
template<int D, int DPAD, int T>
__global__ __launch_bounds__(256) void dist_topk(
    const float* __restrict__ mem,    // [N][D]
    const float* __restrict__ upd,    // [64][D]
    const int*   __restrict__ rowmap, // [N]
    const float* __restrict__ Qt,     // [DPAD][64] normalized queries, k-major
    float* __restrict__ cand_v,       // [64][nblk][T]
    int*   __restrict__ cand_i)
{
  __shared__ float Qs[KT * 64];       // [k][q]
  __shared__ float Ms[KT * 64];       // [k][r]
  __shared__ float sims[64 * 65];     // [q][r] padded
  __shared__ float rsq[64 * 4];
  __shared__ float rinv[64];

  const int t   = threadIdx.x;
  const int bid = blockIdx.x;
  const int r0  = bid * 64;
  const int tx  = t & 15;             // row group
  const int ty  = t >> 4;             // query group
  const int lrow = t >> 2;            // 0..63 : row this thread loads
  const int lk4  = t & 3;             // k phase

  const int gr = r0 + lrow;
  const int u  = rowmap[gr];
  const float* rowptr = (u >= 0) ? (upd + (size_t)u * D) : (mem + (size_t)gr * D);

  float acc[4][4] = {{0.f}};
  float sq = 0.f;

  for (int k0 = 0; k0 < DPAD; k0 += KT) {
    // load memory-row tile -> Ms[k][r], fuse sum of squares
    #pragma unroll
    for (int i = 0; i < 8; ++i) {
      int kk = lk4 + 4 * i;           // 0..31
      int k  = k0 + kk;
      float v = (k < D) ? rowptr[k] : 0.f;
      Ms[kk * 64 + lrow] = v;
      sq += v * v;
    }
    // load query tile (contiguous slab of Qt)
    {
      const float4* src = reinterpret_cast<const float4*>(Qt + k0 * 64);
      float4* dst = reinterpret_cast<float4*>(Qs);
      dst[t * 2]     = src[t * 2];
      dst[t * 2 + 1] = src[t * 2 + 1];
    }
    __syncthreads();
    #pragma unroll 8
    for (int kk = 0; kk < KT; ++kk) {
      float4 a = reinterpret_cast<const float4*>(Qs + kk * 64)[ty];
      float4 b = reinterpret_cast<const float4*>(Ms + kk * 64)[tx];
      float av[4] = {a.x, a.y, a.z, a.w};
      float bv[4] = {b.x, b.y, b.z, b.w};
      #pragma unroll
      for (int qi = 0; qi < 4; ++qi)
        #pragma unroll
        for (int rj = 0; rj < 4; ++rj)
          acc[qi][rj] += av[qi] * bv[rj];
    }
    __syncthreads();
  }

  // per-row inverse norms
  rsq[lrow * 4 + lk4] = sq;
  __syncthreads();
  if (t < 64) {
    float s = rsq[t * 4] + rsq[t * 4 + 1] + rsq[t * 4 + 2] + rsq[t * 4 + 3];
    rinv[t] = 1.f / fmaxf(sqrtf(s), EPSN);
  }
  __syncthreads();

  // normalized sims -> LDS
  #pragma unroll
  for (int qi = 0; qi < 4; ++qi)
    #pragma unroll
    for (int rj = 0; rj < 4; ++rj)
      sims[(ty * 4 + qi) * 65 + (tx * 4 + rj)] = acc[qi][rj] * rinv[tx * 4 + rj];
  __syncthreads();

  // per-query top-T within this 64-row chunk
  if (t < 64) {
    float lv[T]; int li[T];
    #pragma unroll
    for (int i = 0; i < T; ++i) { lv[i] = -FLT_MAX; li[i] = 0x7fffffff; }
    const float* srow = sims + t * 65;
    for (int r = 0; r < 64; ++r) topk_insert<T>(srow[r], r0 + r, lv, li);
    size_t base = ((size_t)t * gridDim.x + bid) * T;
    #pragma unroll
    for (int i = 0; i < T; ++i) { cand_v[base + i] = lv[i]; cand_i[base + i] = li[i]; }
  }
}

// ---------------- merge block candidates -> global top-T per query --------
template<int T>
__global__ __launch_bounds__(64) void merge_topk(
    const float* __restrict__ cand_v, const int* __restrict__ cand_i,
    int nc, int* __restrict__ topout)   // topout stride 6
{
  __shared__ float sv[64 * T];
  __shared__ int   si[64 * T];
  const int q = blockIdx.x, l = threadIdx.x;
  float lv[T]; int li[T];
  #pragma unroll
  for (int i = 0; i < T; ++i) { lv[i] = -FLT_MAX; li[i] = 0x7fffffff; }
  const float* cv = cand_v + (size_t)q * nc;
  const int*   ci = cand_i + (size_t)q * nc;
  for (int c = l; c < nc; c += 64) topk_insert<T>(cv[c], ci[c], lv, li);
  #pragma unroll
  for (int i = 0; i < T; ++i) { sv[l * T + i] = lv[i]; si[l * T + i] = li[i]; }
  __syncthreads();
  if (l == 0) {
    float fv[T]; int fi[T];
    #pragma unroll
    for (int i = 0; i < T; ++i) { fv[i] = -FLT_MAX; fi[i] = 0x7fffffff; }
    for (int c = 0; c < 64 * T; ++c) topk_insert<T>(sv[c], si[c], fv, fi);
    #pragma unroll
    for (int i = 0; i < T; ++i) topout[q * 6 + i] = fi[i];
  }
}

// ---------------- losses ---------------------------------------------------
__global__ __launch_bounds__(384) void loss_softmax_kernel(
    const int* __restrict__ topfeat, const int* __restrict__ rowmap,
    const float* __restrict__ fc1m, const float* __restrict__ fc1U,
    const float* __restrict__ fc2m, const float* __restrict__ fc2U,
    float* __restrict__ out)
{
  __shared__ float sbuf[8];
  int p = blockIdx.x;                // 0..319
  int q = p / 5, j = p % 5 + 1;
  int row = topfeat[q * 6 + j];
  int u = rowmap[row];
  const float* r1 = (u >= 0) ? (fc1U + (size_t)u * CC) : (fc1m + (size_t)row * CC);
  const float* r2 = (u >= 0) ? (fc2U + (size_t)u * CC) : (fc2m + (size_t)row * CC);
  int t = threadIdx.x;
  float v = (t < CC) ? fabsf(r1[t] - r2[t]) : 0.f;
  float s = blockReduceSum(v, sbuf);
  if (t == 0) atomicAdd(out, s * (1.f / (320.f * 345.f)));
}

__global__ __launch_bounds__(256) void loss_feature_kernel(
    const int* __restrict__ topfc1, const int* __restrict__ topfc2,
    const int* __restrict__ rowmap, const float* __restrict__ featm,
    const float* __restrict__ featU, float* __restrict__ out)
{
  __shared__ float sbuf[8];
  int p = blockIdx.x;                // 0..255
  int q = p / 4, j = p % 4 + 1;
  int ra = topfc1[q * 6 + j], rb = topfc2[q * 6 + j];
  int ua = rowmap[ra], ub = rowmap[rb];
  const float* A = (ua >= 0) ? (featU + (size_t)ua * DF) : (featm + (size_t)ra * DF);
  const float* Bp = (ub >= 0) ? (featU + (size_t)ub * DF) : (featm + (size_t)rb * DF);
  int t = threadIdx.x;               // 256 threads == DF
  float a = A[t], b = Bp[t];
  float saa = blockReduceSum(a * a, sbuf);
  float sbb = blockReduceSum(b * b, sbuf);
  float sab = blockReduceSum(a * b, sbuf);
  if (t == 0) {
    float fd = 0.5f * (1.f - sab / (fmaxf(sqrtf(saa), EPSN) * fmaxf(sqrtf(sbb), EPSN)));
    atomicAdd(out + 1, fd * (1.f / 256.f));
  }
}

// ---------------- launch ---------------------------------------------------
extern "C" void kernel_launch(void* const* d_in, const int* in_sizes, int n_in,
                              void* d_out, int out_size, void* d_ws, size_t ws_size,
                              hipStream_t stream)
{
  const float* tf    = (const float*)d_in[0];
  const float* fc1   = (const float*)d_in[1];
  const float* fc2   = (const float*)d_in[2];
  const int*   idx   = (const int*)d_in[3];
  const float* featm = (const float*)d_in[4];
  const float* fc1m  = (const float*)d_in[5];
  const float* fc2m  = (const float*)d_in[6];
  float* out = (float*)d_out;

  const int N    = in_sizes[4] / DF;   // 200000
  const int nblk = N / 64;             // 3125

  char* w = (char*)d_ws;
  auto alloc = [&](size_t bytes) {
    char* p = w;
    w += (bytes + 255) & ~(size_t)255;
    return (void*)p;
  };
  float* Qt_feat = (float*)alloc((size_t)DF * NQ * 4);
  float* Qt_fc1  = (float*)alloc((size_t)CPADD * NQ * 4);
  float* Qt_fc2  = (float*)alloc((size_t)CPADD * NQ * 4);
  float* featU   = (float*)alloc((size_t)NQ * DF * 4);
  float* fc1U    = (float*)alloc((size_t)NQ * CC * 4);
  float* fc2U    = (float*)alloc((size_t)NQ * CC * 4);
  int*   rowmap  = (int*)alloc((size_t)N * 4);
  int*   topfeat = (int*)alloc(NQ * 6 * 4);
  int*   topfc1  = (int*)alloc(NQ * 6 * 4);
  int*   topfc2  = (int*)alloc(NQ * 6 * 4);
  float* cand_v  = (float*)alloc((size_t)NQ * nblk * 6 * 4);
  int*   cand_i  = (int*)alloc((size_t)NQ * nblk * 6 * 4);

  hipMemsetAsync(d_out, 0, 2 * sizeof(float), stream);
  fill_rowmap<<<(N + 255) / 256, 256, 0, stream>>>(rowmap, N);
  prep_kernel<<<NQ, 384, 0, stream>>>(tf, fc1, fc2, idx, featm, fc1m, fc2m,
      Qt_feat, Qt_fc1, Qt_fc2, featU, fc1U, fc2U, rowmap);

  // feature distances: top-6 (drop first, keep 5)
  dist_topk<DF, DF, 6><<<nblk, 256, 0, stream>>>(featm, featU, rowmap, Qt_feat, cand_v, cand_i);
  merge_topk<6><<<NQ, 64, 0, stream>>>(cand_v, cand_i, nblk * 6, topfeat);

  // fc1 distances: top-5 (drop first, keep 4)
  dist_topk<CC, CPADD, 5><<<nblk, 256, 0, stream>>>(fc1m, fc1U, rowmap, Qt_fc1, cand_v, cand_i);
  merge_topk<5><<<NQ, 64, 0, stream>>>(cand_v, cand_i, nblk * 5, topfc1);

  // fc2 distances: top-5
  dist_topk<CC, CPADD, 5><<<nblk, 256, 0, stream>>>(fc2m, fc2U, rowmap, Qt_fc2, cand_v, cand_i);
  merge_topk<5><<<NQ, 64, 0, stream>>>(cand_v, cand_i, nblk * 5, topfc2);

  loss_softmax_kernel<<<320, 384, 0, stream>>>(topfeat, rowmap, fc1m, fc1U, fc2m, fc2U, out);
  loss_feature_kernel<<<256, 256, 0, stream>>>(topfc1, topfc2, rowmap, featm, featU, out);
}

// Round 2
// 1014.874 us; speedup vs baseline: 1.2644x; 1.2644x over previous
//
#include <hip/hip_runtime.h>
#include <hip/hip_bf16.h>
#include <float.h>
#include <math.h>

#define NQ    64      // batch / query count
#define DF    256     // feature dim
#define CC    345     // class dim
#define KSF   8       // 256/32 k-steps
#define KSC   11      // ceil(345/32) k-steps (padded to 352)
#define NBLK  1563    // ceil(200000/128)
#define EPSN  1e-12f

typedef __attribute__((ext_vector_type(8))) short short8;
typedef __attribute__((ext_vector_type(4))) float f32x4;

// ---------------- block-wide reductions -----------------------------------
__device__ __forceinline__ float blockReduceSum(float v, float* sbuf) {
  __syncthreads();
  #pragma unroll
  for (int o = 32; o > 0; o >>= 1) v += __shfl_down(v, o);
  int w = threadIdx.x >> 6;
  if ((threadIdx.x & 63) == 0) sbuf[w] = v;
  __syncthreads();
  if (threadIdx.x == 0) {
    float s = 0.f;
    int nw = blockDim.x >> 6;
    for (int i = 0; i < nw; ++i) s += sbuf[i];
    sbuf[0] = s;
  }
  __syncthreads();
  return sbuf[0];
}

__device__ __forceinline__ float blockReduceMax(float v, float* sbuf) {
  __syncthreads();
  #pragma unroll
  for (int o = 32; o > 0; o >>= 1) v = fmaxf(v, __shfl_down(v, o));
  int w = threadIdx.x >> 6;
  if ((threadIdx.x & 63) == 0) sbuf[w] = v;
  __syncthreads();
  if (threadIdx.x == 0) {
    float s = -FLT_MAX;
    int nw = blockDim.x >> 6;
    for (int i = 0; i < nw; ++i) s = fmaxf(s, sbuf[i]);
    sbuf[0] = s;
  }
  __syncthreads();
  return sbuf[0];
}

// ------------- top-k insert, list sorted (value desc, index asc) ----------
template<int T>
__device__ __forceinline__ void topk_insert(float v, int id, float (&lv)[T], int (&li)[T]) {
  if (!((v > lv[T-1]) || (v == lv[T-1] && id < li[T-1]))) return;
  #pragma unroll
  for (int p = T-1; p > 0; --p) {
    bool up = (v > lv[p-1]) || (v == lv[p-1] && id < li[p-1]);
    if (up) { lv[p] = lv[p-1]; li[p] = li[p-1]; }
    else    { lv[p] = v; li[p] = id; return; }
  }
  lv[0] = v; li[0] = id;
}

template<int T>
__device__ __forceinline__ void merge4(const float* sv, const int* si, int t,
                                       float* dv, int* di) {
  float fv[T]; int fi[T];
  #pragma unroll
  for (int i = 0; i < T; ++i) { fv[i] = -FLT_MAX; fi[i] = 0x7fffffff; }
  for (int s = 0; s < 4; ++s)
    #pragma unroll
    for (int i = 0; i < T; ++i)
      topk_insert<T>(sv[(t*4+s)*T+i], si[(t*4+s)*T+i], fv, fi);
  #pragma unroll
  for (int i = 0; i < T; ++i) { dv[t*T+i] = fv[i]; di[t*T+i] = fi[i]; }
}

// ---------------- rowmap fill ---------------------------------------------
__global__ void fill_rowmap(int* rowmap, int n) {
  int i = blockIdx.x * blockDim.x + threadIdx.x;
  if (i < n) rowmap[i] = -1;
}

// -------- prep: softmax, normalize queries -> MFMA A-frag pack, updates ---
__global__ __launch_bounds__(384) void prep_kernel(
    const float* __restrict__ tf, const float* __restrict__ fc1,
    const float* __restrict__ fc2, const int* __restrict__ idx,
    const float* __restrict__ featm, const float* __restrict__ fc1m,
    const float* __restrict__ fc2m,
    short* __restrict__ Qp_feat,   // [4][KSF][64][8] bf16 A-fragments
    short* __restrict__ Qp_fc1,    // [4][KSC][64][8]
    short* __restrict__ Qp_fc2,
    float* __restrict__ featU, float* __restrict__ fc1U, float* __restrict__ fc2U,
    int* __restrict__ rowmap)
{
  __shared__ float sbuf[8];
  const int b = blockIdx.x, t = threadIdx.x;
  const int trow = idx[b];
  const int qt = b >> 4, qr = b & 15;

  // ---- feature ----
  {
    float x = (t < DF) ? tf[b*DF + t] : 0.f;
    float ss = blockReduceSum(x*x, sbuf);
    float inv = 1.f / fmaxf(sqrtf(ss), EPSN);
    if (t < DF) {
      featU[b*DF + t] = 0.9f * featm[(size_t)trow*DF + t] + 0.1f * x;
      int ks = t >> 5, lg = (t >> 3) & 3, j = t & 7;
      int lane = qr + lg*16;
      union { __hip_bfloat16 h; short s; } cv;
      cv.h = __float2bfloat16(x * inv);
      Qp_feat[((qt*KSF + ks)*64 + lane)*8 + j] = cv.s;
    }
  }
  // ---- fc1 ----
  {
    float y = (t < CC) ? fc1[b*CC + t] : -FLT_MAX;
    float mx = blockReduceMax(y, sbuf);
    float e = (t < CC) ? expf(y - mx) : 0.f;
    float se = blockReduceSum(e, sbuf);
    float s = e / se;
    float s2 = blockReduceSum(s*s, sbuf);
    float inv2 = 1.f / fmaxf(sqrtf(s2), EPSN);
    if (t < CC) fc1U[b*CC + t] = 0.9f * fc1m[(size_t)trow*CC + t] + 0.1f * s;
    if (t < KSC*32) {
      int ks = t >> 5, lg = (t >> 3) & 3, j = t & 7;
      int lane = qr + lg*16;
      union { __hip_bfloat16 h; short s; } cv;
      cv.h = __float2bfloat16((t < CC) ? s * inv2 : 0.f);
      Qp_fc1[((qt*KSC + ks)*64 + lane)*8 + j] = cv.s;
    }
  }
  // ---- fc2 ----
  {
    float y = (t < CC) ? fc2[b*CC + t] : -FLT_MAX;
    float mx = blockReduceMax(y, sbuf);
    float e = (t < CC) ? expf(y - mx) : 0.f;
    float se = blockReduceSum(e, sbuf);
    float s = e / se;
    float s2 = blockReduceSum(s*s, sbuf);
    float inv2 = 1.f / fmaxf(sqrtf(s2), EPSN);
    if (t < CC) fc2U[b*CC + t] = 0.9f * fc2m[(size_t)trow*CC + t] + 0.1f * s;
    if (t < KSC*32) {
      int ks = t >> 5, lg = (t >> 3) & 3, j = t & 7;
      int lane = qr + lg*16;
      union { __hip_bfloat16 h; short s; } cv;
      cv.h = __float2bfloat16((t < CC) ? s * inv2 : 0.f);
      Qp_fc2[((qt*KSC + ks)*64 + lane)*8 + j] = cv.s;
    }
  }
  if (t == 0) rowmap[trow] = b;
}

// -------- MFMA cos-sim (64 q x 128 rows per block) + fused block top-T ----
template<int D, int KS, int T>
__global__ __launch_bounds__(256) void dist_topk_mfma(
    const float* __restrict__ mem, const float* __restrict__ upd,
    const int* __restrict__ rowmap, const short8* __restrict__ Qp,
    float* __restrict__ cand_v, int* __restrict__ cand_i, int N)
{
  __shared__ float sims[64 * 131];    // [q][row-in-block], pad 131 (2-way max)
  const int t  = threadIdx.x;
  const int w  = t >> 6, l = t & 63;
  const int lc = l & 15, lg = l >> 4; // col-in-frag / k-group
  const int r0b = blockIdx.x * 128;
  const int r0  = r0b + w * 32;

  // per-lane row pointers for the 2 row-tiles (redirect updated rows)
  const float* rp[2]; bool valid[2];
  #pragma unroll
  for (int rt = 0; rt < 2; ++rt) {
    int gr = r0 + rt*16 + lc;
    valid[rt] = (gr < N);
    int cg = valid[rt] ? gr : N - 1;
    int u = rowmap[cg];
    rp[rt] = (u >= 0) ? (upd + (size_t)u * D) : (mem + (size_t)cg * D);
  }

  f32x4 acc[4][2];
  #pragma unroll
  for (int qt = 0; qt < 4; ++qt)
    #pragma unroll
    for (int rt = 0; rt < 2; ++rt) acc[qt][rt] = (f32x4){0.f, 0.f, 0.f, 0.f};
  float sq[2] = {0.f, 0.f};

  #pragma unroll
  for (int ks = 0; ks < KS; ++ks) {
    short8 bfr[2];
    #pragma unroll
    for (int rt = 0; rt < 2; ++rt) {
      float v[8];
      if (D % 32 != 0 && ks == KS - 1) {      // guarded tail (fc banks)
        #pragma unroll
        for (int j = 0; j < 8; ++j) {
          int k = ks*32 + lg*8 + j;
          v[j] = (k < D) ? rp[rt][k] : 0.f;
        }
      } else {
        const float* p = rp[rt] + ks*32 + lg*8;
        #pragma unroll
        for (int j = 0; j < 8; ++j) v[j] = p[j];
      }
      #pragma unroll
      for (int j = 0; j < 8; ++j) sq[rt] += v[j] * v[j];
      union { short8 s8; __hip_bfloat162 h2[4]; } fb;
      #pragma unroll
      for (int j = 0; j < 4; ++j)
        fb.h2[j] = __float22bfloat162_rn(make_float2(v[2*j], v[2*j+1]));
      bfr[rt] = fb.s8;
    }
    #pragma unroll
    for (int qt = 0; qt < 4; ++qt) {
      short8 af = Qp[(qt*KS + ks)*64 + l];
      acc[qt][0] = __builtin_amdgcn_mfma_f32_16x16x32_bf16(af, bfr[0], acc[qt][0], 0, 0, 0);
      acc[qt][1] = __builtin_amdgcn_mfma_f32_16x16x32_bf16(af, bfr[1], acc[qt][1], 0, 0, 0);
    }
  }

  // row inverse-norms: lanes l, l^16, l^32, l^48 hold partials of same row
  float rinv[2];
  #pragma unroll
  for (int rt = 0; rt < 2; ++rt) {
    float s = sq[rt];
    s += __shfl_xor(s, 16);
    s += __shfl_xor(s, 32);
    rinv[rt] = 1.f / fmaxf(sqrtf(s), EPSN);
  }

  // D-frag: col(mem-row) = lane&15, row(query) = (lane>>4)*4 + reg
  #pragma unroll
  for (int qt = 0; qt < 4; ++qt)
    #pragma unroll
    for (int rt = 0; rt < 2; ++rt)
      #pragma unroll
      for (int r = 0; r < 4; ++r) {
        int q = qt*16 + lg*4 + r;
        float sv = valid[rt] ? acc[qt][rt][r] * rinv[rt] : -FLT_MAX;
        sims[q*131 + w*32 + rt*16 + lc] = sv;
      }
  __syncthreads();

  // block top-T: 4 threads per query, 32 rows each, then merge
  const int q = t & 63, quarter = t >> 6;
  float lv[T]; int li[T];
  #pragma unroll
  for (int i = 0; i < T; ++i) { lv[i] = -FLT_MAX; li[i] = 0x7fffffff; }
  {
    const float* srow = sims + q*131 + quarter*32;
    for (int c = 0; c < 32; ++c) topk_insert<T>(srow[c], r0b + quarter*32 + c, lv, li);
  }
  __syncthreads();                     // all reads of sims done
  float* lv_s = sims;                  // reuse sims as list buffer
  int*   li_s = (int*)(sims + 64*4*T);
  #pragma unroll
  for (int i = 0; i < T; ++i) {
    lv_s[(q*4 + quarter)*T + i] = lv[i];
    li_s[(q*4 + quarter)*T + i] = li[i];
  }
  __syncthreads();
  if (t < 64) {
    float fv[T]; int fi[T];
    #pragma unroll
    for (int i = 0; i < T; ++i) { fv[i] = -FLT_MAX; fi[i] = 0x7fffffff; }
    for (int s = 0; s < 4; ++s)
      #pragma unroll
      for (int i = 0; i < T; ++i)
        topk_insert<T>(lv_s[(t*4+s)*T+i], li_s[(t*4+s)*T+i], fv, fi);
    size_t base = ((size_t)t * gridDim.x + blockIdx.x) * T;
    #pragma unroll
    for (int i = 0; i < T; ++i) { cand_v[base+i] = fv[i]; cand_i[base+i] = fi[i]; }
  }
}

// -------- hierarchical merge: block candidates -> global top-T per query --
template<int T>
__global__ __launch_bounds__(256) void merge_topk(
    const float* __restrict__ cv, const int* __restrict__ ci,
    int nc, int* __restrict__ topout)      // topout stride 6
{
  __shared__ float sv[256*T]; __shared__ int si[256*T];
  __shared__ float sv2[64*T]; __shared__ int si2[64*T];
  const int q = blockIdx.x, t = threadIdx.x;
  float lv[T]; int li[T];
  #pragma unroll
  for (int i = 0; i < T; ++i) { lv[i] = -FLT_MAX; li[i] = 0x7fffffff; }
  const float* v  = cv + (size_t)q * nc;
  const int*   ii = ci + (size_t)q * nc;
  for (int c = t; c < nc; c += 256) topk_insert<T>(v[c], ii[c], lv, li);
  #pragma unroll
  for (int i = 0; i < T; ++i) { sv[t*T+i] = lv[i]; si[t*T+i] = li[i]; }
  __syncthreads();
  if (t < 64) merge4<T>(sv, si, t, sv2, si2);
  __syncthreads();
  if (t < 16) merge4<T>(sv2, si2, t, sv, si);
  __syncthreads();
  if (t < 4)  merge4<T>(sv, si, t, sv2, si2);
  __syncthreads();
  if (t == 0) {
    float fv[T]; int fi[T];
    #pragma unroll
    for (int i = 0; i < T; ++i) { fv[i] = -FLT_MAX; fi[i] = 0x7fffffff; }
    for (int s = 0; s < 4; ++s)
      #pragma unroll
      for (int i = 0; i < T; ++i)
        topk_insert<T>(sv2[s*T+i], si2[s*T+i], fv, fi);
    #pragma unroll
    for (int i = 0; i < T; ++i) topout[q*6 + i] = fi[i];
  }
}

// ---------------- losses ---------------------------------------------------
__global__ __launch_bounds__(384) void loss_softmax_kernel(
    const int* __restrict__ topfeat, const int* __restrict__ rowmap,
    const float* __restrict__ fc1m, const float* __restrict__ fc1U,
    const float* __restrict__ fc2m, const float* __restrict__ fc2U,
    float* __restrict__ out)
{
  __shared__ float sbuf[8];
  int p = blockIdx.x;                // 0..319
  int q = p / 5, j = p % 5 + 1;
  int row = topfeat[q*6 + j];
  int u = rowmap[row];
  const float* r1 = (u >= 0) ? (fc1U + (size_t)u * CC) : (fc1m + (size_t)row * CC);
  const float* r2 = (u >= 0) ? (fc2U + (size_t)u * CC) : (fc2m + (size_t)row * CC);
  int t = threadIdx.x;
  float v = (t < CC) ? fabsf(r1[t] - r2[t]) : 0.f;
  float s = blockReduceSum(v, sbuf);
  if (t == 0) atomicAdd(out, s * (1.f / (320.f * 345.f)));
}

__global__ __launch_bounds__(256) void loss_feature_kernel(
    const int* __restrict__ topfc1, const int* __restrict__ topfc2,
    const int* __restrict__ rowmap, const float* __restrict__ featm,
    const float* __restrict__ featU, float* __restrict__ out)
{
  __shared__ float sbuf[8];
  int p = blockIdx.x;                // 0..255
  int q = p / 4, j = p % 4 + 1;
  int ra = topfc1[q*6 + j], rb = topfc2[q*6 + j];
  int ua = rowmap[ra], ub = rowmap[rb];
  const float* A  = (ua >= 0) ? (featU + (size_t)ua * DF) : (featm + (size_t)ra * DF);
  const float* Bp = (ub >= 0) ? (featU + (size_t)ub * DF) : (featm + (size_t)rb * DF);
  int t = threadIdx.x;               // 256 == DF
  float a = A[t], b = Bp[t];
  float saa = blockReduceSum(a*a, sbuf);
  float sbb = blockReduceSum(b*b, sbuf);
  float sab = blockReduceSum(a*b, sbuf);
  if (t == 0) {
    float fd = 0.5f * (1.f - sab / (fmaxf(sqrtf(saa), EPSN) * fmaxf(sqrtf(sbb), EPSN)));
    atomicAdd(out + 1, fd * (1.f / 256.f));
  }
}

// ---------------- launch ---------------------------------------------------
extern "C" void kernel_launch(void* const* d_in, const int* in_sizes, int n_in,
                              void* d_out, int out_size, void* d_ws, size_t ws_size,
                              hipStream_t stream)
{
  const float* tf    = (const float*)d_in[0];
  const float* fc1   = (const float*)d_in[1];
  const float* fc2   = (const float*)d_in[2];
  const int*   idx   = (const int*)d_in[3];
  const float* featm = (const float*)d_in[4];
  const float* fc1m  = (const float*)d_in[5];
  const float* fc2m  = (const float*)d_in[6];
  float* out = (float*)d_out;

  const int N = in_sizes[4] / DF;      // 200000

  char* w = (char*)d_ws;
  auto alloc = [&](size_t bytes) {
    char* p = w;
    w += (bytes + 255) & ~(size_t)255;
    return (void*)p;
  };
  short* Qp_feat = (short*)alloc((size_t)4 * KSF * 64 * 8 * 2);
  short* Qp_fc1  = (short*)alloc((size_t)4 * KSC * 64 * 8 * 2);
  short* Qp_fc2  = (short*)alloc((size_t)4 * KSC * 64 * 8 * 2);
  float* featU   = (float*)alloc((size_t)NQ * DF * 4);
  float* fc1U    = (float*)alloc((size_t)NQ * CC * 4);
  float* fc2U    = (float*)alloc((size_t)NQ * CC * 4);
  int*   rowmap  = (int*)alloc((size_t)N * 4);
  int*   topfeat = (int*)alloc(NQ * 6 * 4);
  int*   topfc1  = (int*)alloc(NQ * 6 * 4);
  int*   topfc2  = (int*)alloc(NQ * 6 * 4);
  float* cand_v  = (float*)alloc((size_t)NQ * NBLK * 6 * 4);
  int*   cand_i  = (int*)alloc((size_t)NQ * NBLK * 6 * 4);

  hipMemsetAsync(d_out, 0, 2 * sizeof(float), stream);
  fill_rowmap<<<(N + 255) / 256, 256, 0, stream>>>(rowmap, N);
  prep_kernel<<<NQ, 384, 0, stream>>>(tf, fc1, fc2, idx, featm, fc1m, fc2m,
      Qp_feat, Qp_fc1, Qp_fc2, featU, fc1U, fc2U, rowmap);

  // feature: top-6 (drop first, keep 5)
  dist_topk_mfma<DF, KSF, 6><<<NBLK, 256, 0, stream>>>(
      featm, featU, rowmap, (const short8*)Qp_feat, cand_v, cand_i, N);
  merge_topk<6><<<NQ, 256, 0, stream>>>(cand_v, cand_i, NBLK * 6, topfeat);

  // fc1: top-5 (drop first, keep 4)
  dist_topk_mfma<CC, KSC, 5><<<NBLK, 256, 0, stream>>>(
      fc1m, fc1U, rowmap, (const short8*)Qp_fc1, cand_v, cand_i, N);
  merge_topk<5><<<NQ, 256, 0, stream>>>(cand_v, cand_i, NBLK * 5, topfc1);

  // fc2: top-5
  dist_topk_mfma<CC, KSC, 5><<<NBLK, 256, 0, stream>>>(
      fc2m, fc2U, rowmap, (const short8*)Qp_fc2, cand_v, cand_i, N);
  merge_topk<5><<<NQ, 256, 0, stream>>>(cand_v, cand_i, NBLK * 5, topfc2);

  loss_softmax_kernel<<<320, 384, 0, stream>>>(topfeat, rowmap, fc1m, fc1U, fc2m, fc2U, out);
  loss_feature_kernel<<<256, 256, 0, stream>>>(topfc1, topfc2, rowmap, featm, featU, out);
}